// Round 4
// baseline (1609.181 us; speedup 1.0000x reference)
//
#include <hip/hip_runtime.h>

typedef unsigned short u16;
typedef unsigned int u32;
typedef __bf16 bf16x8 __attribute__((ext_vector_type(8)));
typedef bf16x8 __attribute__((may_alias)) bf16x8a;   // TBAA-safe vector loads
typedef float f32x4 __attribute__((ext_vector_type(4)));

#define BB 32
#define SS 1024
#define HH 128
#define DD 256

__device__ __forceinline__ float b2f(u16 u) {
    u32 v = ((u32)u) << 16;
    return __builtin_bit_cast(float, v);
}
__device__ __forceinline__ u16 f2b(float f) {
    u32 u = __builtin_bit_cast(u32, f);
    u32 r = (u + 0x7fffu + ((u >> 16) & 1u)) >> 16;   // RNE
    return (u16)r;
}
__device__ __forceinline__ float sig_fast(float x) {
    return __builtin_amdgcn_rcpf(1.0f + __builtin_amdgcn_exp2f(-1.4426950408889634f * x));
}
__device__ __forceinline__ float tanh_fast(float x) {
    return 2.0f * sig_fast(2.0f * x) - 1.0f;
}

// ---------------------------------------------------------------------------
// fp32 -> bf16 conversion (grid-stride, float4 / ushort4)
// ---------------------------------------------------------------------------
__global__ __launch_bounds__(256) void conv_f32_bf16(
    const float* __restrict__ src, u16* __restrict__ dst, int n4)
{
    for (int i = blockIdx.x * 256 + threadIdx.x; i < n4; i += gridDim.x * 256) {
        float4 v = ((const float4*)src)[i];
        ushort4 o;
        o.x = f2b(v.x); o.y = f2b(v.y); o.z = f2b(v.z); o.w = f2b(v.w);
        ((ushort4*)dst)[i] = o;
    }
}

// ---------------------------------------------------------------------------
// fp32 -> bf16 with gate-interleave row permutation for [512][128] matrices:
// input row r = gate*128 + u  ->  output row u*4 + gate. Used for Wih and Whh
// so that MFMA output columns come out gate-interleaved (4 gates of one
// hidden unit in adjacent columns -> in-quad register transpose in the scan).
// ---------------------------------------------------------------------------
__global__ __launch_bounds__(256) void conv_perm512(
    const float* __restrict__ src, u16* __restrict__ dst)
{
    for (int i = blockIdx.x * 256 + threadIdx.x; i < 512 * 128 / 4; i += gridDim.x * 256) {
        int r = i >> 5;             // input row (128 elems = 32 float4)
        int c4 = i & 31;
        int rp = ((r & 127) << 2) | (r >> 7);
        float4 v = ((const float4*)src)[i];
        ushort4 o;
        o.x = f2b(v.x); o.y = f2b(v.y); o.z = f2b(v.z); o.w = f2b(v.w);
        *(ushort4*)&dst[rp * 128 + c4 * 4] = o;
    }
}

// ---------------------------------------------------------------------------
// GEMM: C[M,N] = A[M,K] * Bt[N,K]^T, bf16 in, fp32 acc, bf16 out.
// 128x128 tile, BK=64, 256 thr = 4 waves (2x2), wave = 64x64.
// MODE 0: plain row-major store [row][col], no bias.
// MODE 1: xg store: row = b*1024+s -> store at [s][b][col] (per-dir buffer),
//         bias added with un-permuted index (cols are gate-interleaved).
// ---------------------------------------------------------------------------
template <int MODE>
__global__ __launch_bounds__(256) void gemm_bt(
    const u16* __restrict__ A, const u16* __restrict__ Bt,
    const float* __restrict__ bias1, const float* __restrict__ bias2,
    u16* __restrict__ Cout, int K, int N)
{
    __shared__ u16 As[128 * 72];   // rows m, padded
    __shared__ u16 Bs[128 * 72];   // rows n, padded
    const int tid = threadIdx.x;
    const int lane = tid & 63, wave = tid >> 6;
    const int wm = wave >> 1, wn = wave & 1;
    const int lo = lane & 15, hi = lane >> 4;
    const int m0 = blockIdx.x * 128, n0 = blockIdx.y * 128;

    f32x4 acc[4][4] = {};

    for (int k0 = 0; k0 < K; k0 += 64) {
        __syncthreads();
#pragma unroll
        for (int i = 0; i < 4; i++) {
            int c = tid + 256 * i;
            int row = c >> 3, kc = (c & 7) * 8;
            *(uint4*)&As[row * 72 + kc] =
                *(const uint4*)&A[(size_t)(m0 + row) * K + k0 + kc];
            *(uint4*)&Bs[row * 72 + kc] =
                *(const uint4*)&Bt[(size_t)(n0 + row) * K + k0 + kc];
        }
        __syncthreads();
#pragma unroll
        for (int ks = 0; ks < 2; ks++) {
            bf16x8 af[4], bfr[4];
#pragma unroll
            for (int i = 0; i < 4; i++)
                af[i] = *(const bf16x8a*)&As[(wm * 64 + i * 16 + lo) * 72 + ks * 32 + hi * 8];
#pragma unroll
            for (int j = 0; j < 4; j++)
                bfr[j] = *(const bf16x8a*)&Bs[(wn * 64 + j * 16 + lo) * 72 + ks * 32 + hi * 8];
#pragma unroll
            for (int i = 0; i < 4; i++)
#pragma unroll
                for (int j = 0; j < 4; j++)
                    acc[i][j] = __builtin_amdgcn_mfma_f32_16x16x32_bf16(
                        af[i], bfr[j], acc[i][j], 0, 0, 0);
        }
    }
    // C layout per 16x16 tile: row = (lane>>4)*4 + reg, col = lane&15
#pragma unroll
    for (int j = 0; j < 4; j++) {
        int col = n0 + wn * 64 + j * 16 + lo;
        float bsum = 0.f;
        if (MODE == 1) {
            int co = ((col & 3) << 7) | (col >> 2);   // un-permute for bias lookup
            bsum = bias1[co] + bias2[co];
        }
#pragma unroll
        for (int i = 0; i < 4; i++) {
            int row0 = m0 + wm * 64 + i * 16 + hi * 4;
#pragma unroll
            for (int r = 0; r < 4; r++) {
                float v = acc[i][j][r] + bsum;
                if (MODE == 1) {
                    int row = row0 + r;                 // = b*1024 + s
                    int sidx = row & 1023, bidx = row >> 10;
                    Cout[(size_t)sidx * (BB * 512) + bidx * 512 + col] = f2b(v);
                } else {
                    Cout[(size_t)(row0 + r) * N + col] = f2b(v);
                }
            }
        }
    }
}

// ---------------------------------------------------------------------------
// In-quad 4x4 transpose: lanes base..base+3 hold V[g][r]; after, lane q holds
// v[r] = V[r][q]. 4 shfl_xor + selects (verified by hand, lanes 0..3).
// ---------------------------------------------------------------------------
__device__ __forceinline__ void transpose4(f32x4& v, int lane) {
    bool c1 = (lane & 1) != 0;
    float s, r;
    s = c1 ? v[0] : v[1]; r = __shfl_xor(s, 1, 64);
    v[0] = c1 ? r : v[0]; v[1] = c1 ? v[1] : r;
    s = c1 ? v[2] : v[3]; r = __shfl_xor(s, 1, 64);
    v[2] = c1 ? r : v[2]; v[3] = c1 ? v[3] : r;
    bool c2 = (lane & 2) != 0;
    s = c2 ? v[0] : v[2]; r = __shfl_xor(s, 2, 64);
    v[0] = c2 ? r : v[0]; v[2] = c2 ? v[2] : r;
    s = c2 ? v[1] : v[3]; r = __shfl_xor(s, 2, 64);
    v[1] = c2 ? r : v[1]; v[3] = c2 ? v[3] : r;
}

__device__ __forceinline__ float lstm_cell(const f32x4& g, float& c) {
    float i_ = sig_fast(g[0]);
    float f_ = sig_fast(g[1]);
    float t_ = tanh_fast(g[2]);
    float o_ = sig_fast(g[3]);
    c = fmaf(f_, c, i_ * t_);
    return o_ * tanh_fast(c);
}

// ---------------------------------------------------------------------------
// MFMA LSTM scan. 4 WGs x 1024 thr (16 waves). WG: dir = wg>>1, batches
// b0 = (wg&1)*16 .. +16. Per step: [16,128] @ [128,512] via MFMA; wave wv
// owns gate-cols [wv*32, wv*32+32) of the PERMUTED (u*4+gate) layout.
// Whh B-frags resident in VGPRs. h double-buffered in LDS (1 barrier/step).
// Gate transpose in-quad -> activations/c-update fully in registers.
// ---------------------------------------------------------------------------
__global__ __launch_bounds__(1024) void lstm_scan_mfma(
    const u16* __restrict__ Whh_p,   // [2][512][128] bf16, rows permuted
    const u16* __restrict__ xg,      // [2][S][B][512] bf16, cols permuted
    u16* __restrict__ hout)          // [B][S][256]; fw->[0:128], bw->[128:256]
{
    const int wg = blockIdx.x;
    const int dir = wg >> 1;
    const int b0 = (wg & 1) * 16;
    const int tid = threadIdx.x;
    const int wv = tid >> 6, lane = tid & 63;
    const int lo = lane & 15, hi = lane >> 4;
    const int q = lane & 3, u2 = (lane >> 2) & 3;
    const int m = hi * 4 + q;            // owned batch row (post-transpose)
    const int u0 = wv * 8 + u2;          // owned hidden unit, nt=0
    const int u1 = u0 + 4;               // nt=1

    // resident Whh B-fragments: rows n = wv*32 + nt*16 + lo, k = ks*32 + hi*8
    bf16x8 wfrag[2][4];
    {
        const u16* wp = Whh_p + (size_t)dir * 512 * 128;
#pragma unroll
        for (int nt = 0; nt < 2; nt++)
#pragma unroll
            for (int ks = 0; ks < 4; ks++)
                wfrag[nt][ks] = *(const bf16x8a*)
                    &wp[(size_t)(wv * 32 + nt * 16 + lo) * 128 + ks * 32 + hi * 8];
    }

    __shared__ u16 hbuf[2][16 * 136];    // double-buffered h (bf16), padded
    {
        u16* hb = &hbuf[0][0];
        for (int i = tid; i < 2 * 16 * 136; i += 1024) hb[i] = 0;
    }

    const u16* xgd = xg + (size_t)dir * SS * (BB * 512);
    const int xoff_m = (b0 + m) * 512;

    float c0 = 0.f, c1s = 0.f;
    int s = dir ? (SS - 1) : 0;
    const int dstep = dir ? -1 : 1;

    uint2 nx0, nx1;
    {
        size_t base = (size_t)s * (BB * 512) + xoff_m;
        nx0 = *(const uint2*)&xgd[base + u0 * 4];
        nx1 = *(const uint2*)&xgd[base + u1 * 4];
    }
    __syncthreads();

    for (int t = 0; t < SS; t++) {
        uint2 x0 = nx0, x1 = nx1;
        int s_next = s + dstep;
        if (t < SS - 1) {   // prefetch next step's xg (one-step latency hiding)
            size_t base = (size_t)s_next * (BB * 512) + xoff_m;
            nx0 = *(const uint2*)&xgd[base + u0 * 4];
            nx1 = *(const uint2*)&xgd[base + u1 * 4];
        }

        const u16* hb = hbuf[t & 1];
        bf16x8 af[4];
#pragma unroll
        for (int ks = 0; ks < 4; ks++)
            af[ks] = *(const bf16x8a*)&hb[lo * 136 + ks * 32 + hi * 8];

        f32x4 acc0 = {}, acc1 = {};
#pragma unroll
        for (int ks = 0; ks < 4; ks++) {
            acc0 = __builtin_amdgcn_mfma_f32_16x16x32_bf16(af[ks], wfrag[0][ks], acc0, 0, 0, 0);
            acc1 = __builtin_amdgcn_mfma_f32_16x16x32_bf16(af[ks], wfrag[1][ks], acc1, 0, 0, 0);
        }

        transpose4(acc0, lane);
        transpose4(acc1, lane);

        // add xg (4 gates of (m,u), adjacent bf16 in permuted layout)
        acc0[0] += b2f((u16)(x0.x & 0xffff)); acc0[1] += b2f((u16)(x0.x >> 16));
        acc0[2] += b2f((u16)(x0.y & 0xffff)); acc0[3] += b2f((u16)(x0.y >> 16));
        acc1[0] += b2f((u16)(x1.x & 0xffff)); acc1[1] += b2f((u16)(x1.x >> 16));
        acc1[2] += b2f((u16)(x1.y & 0xffff)); acc1[3] += b2f((u16)(x1.y >> 16));

        float h0 = lstm_cell(acc0, c0);
        float h1 = lstm_cell(acc1, c1s);

        u16 hb0 = f2b(h0), hb1 = f2b(h1);
        u16* hw = &hbuf[(t + 1) & 1][0];
        hw[m * 136 + u0] = hb0;
        hw[m * 136 + u1] = hb1;
        size_t go = ((size_t)(b0 + m) * SS + s) * DD + dir * HH;
        hout[go + u0] = hb0;
        hout[go + u1] = hb1;

        __syncthreads();
        s = s_next;
    }
}

// ---------------------------------------------------------------------------
// V transpose: v[b][s][d] -> vT[b][d][s] via LDS tiles (64x64)
// ---------------------------------------------------------------------------
__global__ __launch_bounds__(256) void transpose_v(
    const u16* __restrict__ v, u16* __restrict__ vT)
{
    __shared__ u16 tile[64 * 72];
    const int b = blockIdx.z, s0 = blockIdx.x * 64, d0 = blockIdx.y * 64;
    const int tid = threadIdx.x;
#pragma unroll
    for (int i = 0; i < 2; i++) {
        int c = tid + 256 * i;
        int sl = c >> 3, dc = (c & 7) * 8;
        *(uint4*)&tile[sl * 72 + dc] =
            *(const uint4*)&v[((size_t)b * SS + s0 + sl) * DD + d0 + dc];
    }
    __syncthreads();
#pragma unroll
    for (int i = 0; i < 2; i++) {
        int c = tid + 256 * i;
        int dl = c >> 3, sc = (c & 7) * 8;
        u32 x0 = (u32)tile[(sc + 0) * 72 + dl] | ((u32)tile[(sc + 1) * 72 + dl] << 16);
        u32 x1 = (u32)tile[(sc + 2) * 72 + dl] | ((u32)tile[(sc + 3) * 72 + dl] << 16);
        u32 x2 = (u32)tile[(sc + 4) * 72 + dl] | ((u32)tile[(sc + 5) * 72 + dl] << 16);
        u32 x3 = (u32)tile[(sc + 6) * 72 + dl] | ((u32)tile[(sc + 7) * 72 + dl] << 16);
        uint4 val; val.x = x0; val.y = x1; val.z = x2; val.w = x3;
        *(uint4*)&vT[((size_t)b * DD + d0 + dl) * SS + s0 + sc] = val;
    }
}

// ---------------------------------------------------------------------------
// Flash attention: WG = (batch, 64-row q tile), 256 thr = 4 waves, each wave
// a 16-row stripe. KV tiles of 32. exp2-domain softmax, scale folded. f32 out.
// ---------------------------------------------------------------------------
__global__ __launch_bounds__(256) void attn_kernel(
    const u16* __restrict__ q, const u16* __restrict__ k,
    const u16* __restrict__ vT, float* __restrict__ out)
{
    __shared__ u16 Ks[32 * 264];   // [s'][d], padded
    __shared__ u16 Vs[256 * 40];   // [d][s'], padded
    __shared__ u16 Ps[64 * 40];    // [q][s'], padded
    const int b = blockIdx.y, q0 = blockIdx.x * 64;
    const int tid = threadIdx.x, wave = tid >> 6, lane = tid & 63;
    const int lo = lane & 15, hi = lane >> 4;
    const float c1 = 0.09016844005556021f;  // log2(e)/16

    bf16x8 qf[8];
    {
        const u16* qp = q + ((size_t)b * SS + q0 + wave * 16 + lo) * DD;
#pragma unroll
        for (int ks = 0; ks < 8; ks++)
            qf[ks] = *(const bf16x8a*)&qp[ks * 32 + hi * 8];
    }
    float m_i[4] = {-1e30f, -1e30f, -1e30f, -1e30f};
    float l_i[4] = {0.f, 0.f, 0.f, 0.f};
    f32x4 o[16] = {};

    for (int t0 = 0; t0 < SS; t0 += 32) {
        __syncthreads();
#pragma unroll
        for (int i = 0; i < 4; i++) {
            int c = tid + 256 * i;
            {
                int row = c >> 5, dc = (c & 31) * 8;
                *(uint4*)&Ks[row * 264 + dc] =
                    *(const uint4*)&k[((size_t)b * SS + t0 + row) * DD + dc];
            }
            {
                int d = c >> 2, sc = (c & 3) * 8;
                *(uint4*)&Vs[d * 40 + sc] =
                    *(const uint4*)&vT[((size_t)b * DD + d) * SS + t0 + sc];
            }
        }
        __syncthreads();

        // S = Q K^T for this wave's 16 rows x 32 cols
        f32x4 sacc[2] = {};
#pragma unroll
        for (int ks = 0; ks < 8; ks++) {
#pragma unroll
            for (int j = 0; j < 2; j++) {
                bf16x8 bfr = *(const bf16x8a*)&Ks[(j * 16 + lo) * 264 + ks * 32 + hi * 8];
                sacc[j] = __builtin_amdgcn_mfma_f32_16x16x32_bf16(qf[ks], bfr, sacc[j], 0, 0, 0);
            }
        }

        // online softmax (exp2 domain)
        float tt[2][4];
#pragma unroll
        for (int j = 0; j < 2; j++)
#pragma unroll
            for (int r = 0; r < 4; r++) tt[j][r] = sacc[j][r] * c1;
        float rm[4];
#pragma unroll
        for (int r = 0; r < 4; r++) rm[r] = fmaxf(tt[0][r], tt[1][r]);
#pragma unroll
        for (int mm = 1; mm <= 8; mm <<= 1)
#pragma unroll
            for (int r = 0; r < 4; r++) rm[r] = fmaxf(rm[r], __shfl_xor(rm[r], mm, 64));
        float al[4], rs[4];
#pragma unroll
        for (int r = 0; r < 4; r++) {
            float mn = fmaxf(m_i[r], rm[r]);
            al[r] = __builtin_amdgcn_exp2f(m_i[r] - mn);
            m_i[r] = mn;
            rs[r] = 0.f;
        }
#pragma unroll
        for (int j = 0; j < 2; j++)
#pragma unroll
            for (int r = 0; r < 4; r++) {
                float p = __builtin_amdgcn_exp2f(tt[j][r] - m_i[r]);
                rs[r] += p;
                Ps[(wave * 16 + hi * 4 + r) * 40 + j * 16 + lo] = f2b(p);
            }
#pragma unroll
        for (int mm = 1; mm <= 8; mm <<= 1)
#pragma unroll
            for (int r = 0; r < 4; r++) rs[r] += __shfl_xor(rs[r], mm, 64);
#pragma unroll
        for (int r = 0; r < 4; r++) l_i[r] = l_i[r] * al[r] + rs[r];
#pragma unroll
        for (int nt = 0; nt < 16; nt++) {
            o[nt][0] *= al[0]; o[nt][1] *= al[1];
            o[nt][2] *= al[2]; o[nt][3] *= al[3];
        }
        // barrier orders the u16 Ps stores against the vector Ps reload
        __syncthreads();
        // O += P V  (wave reads only its own 16-row stripe of Ps)
        bf16x8 pa = *(const bf16x8a*)&Ps[(wave * 16 + lo) * 40 + hi * 8];
#pragma unroll
        for (int nt = 0; nt < 16; nt++) {
            bf16x8 bv = *(const bf16x8a*)&Vs[(nt * 16 + lo) * 40 + hi * 8];
            o[nt] = __builtin_amdgcn_mfma_f32_16x16x32_bf16(pa, bv, o[nt], 0, 0, 0);
        }
    }
    float inv[4];
#pragma unroll
    for (int r = 0; r < 4; r++) inv[r] = __builtin_amdgcn_rcpf(l_i[r]);
#pragma unroll
    for (int nt = 0; nt < 16; nt++)
#pragma unroll
        for (int r = 0; r < 4; r++) {
            int row = q0 + wave * 16 + hi * 4 + r;
            int col = nt * 16 + lo;
            out[((size_t)b * SS + row) * DD + col] = o[nt][r] * inv[r];
        }
}

// ---------------------------------------------------------------------------
extern "C" void kernel_launch(void* const* d_in, const int* in_sizes, int n_in,
                              void* d_out, int out_size, void* d_ws, size_t ws_size,
                              hipStream_t stream)
{
    (void)in_sizes; (void)n_in; (void)out_size;
    const float* x      = (const float*)d_in[0];
    const float* fw_Wih = (const float*)d_in[1];
    const float* fw_Whh = (const float*)d_in[2];
    const float* fw_bih = (const float*)d_in[3];
    const float* fw_bhh = (const float*)d_in[4];
    const float* bw_Wih = (const float*)d_in[5];
    const float* bw_Whh = (const float*)d_in[6];
    const float* bw_bih = (const float*)d_in[7];
    const float* bw_bhh = (const float*)d_in[8];
    const float* Wq = (const float*)d_in[9];
    const float* Wk = (const float*)d_in[10];
    const float* Wv = (const float*)d_in[11];

    // Workspace layout (total 143,523,840 B; ws proven >= 201 MB in r1/r2):
    //   [0, 67108864)    xg bf16 [2][S][B][512], cols gate-interleaved
    //                    (dead after scan; vb aliases)
    //   +67108864        h   bf16 [32768][256]
    //   +83886080        qb
    //   +100663296       kb
    //   +117440512       vT
    //   +134217728       x16 bf16 [32768][128]
    //   +142606336       weights bf16: fwWih_p, bwWih_p, wq, wk, wv,
    //                    fwWhh_p, bwWhh_p (131072 B each)
    if (ws_size < 143523840ULL) return;

    char* ws = (char*)d_ws;
    u16* xg  = (u16*)ws;
    u16* h   = (u16*)(ws + 67108864);
    u16* qb  = (u16*)(ws + 83886080);
    u16* kb  = (u16*)(ws + 100663296);
    u16* vT  = (u16*)(ws + 117440512);
    u16* x16 = (u16*)(ws + 134217728);
    u16* wfih16 = (u16*)(ws + 142606336);
    u16* wbih16 = (u16*)(ws + 142606336 + 131072);
    u16* wq16   = (u16*)(ws + 142606336 + 262144);
    u16* wk16   = (u16*)(ws + 142606336 + 393216);
    u16* wv16   = (u16*)(ws + 142606336 + 524288);
    u16* whh16  = (u16*)(ws + 142606336 + 655360);   // [2][512][128]
    u16* vb = (u16*)ws;                              // aliases xg (dead after scan)

    // fp32 -> bf16 conversions (weights row-permuted where gate-interleave needed)
    conv_f32_bf16<<<1024, 256, 0, stream>>>(x, x16, (BB * SS * HH) / 4);
    conv_perm512<<<64, 256, 0, stream>>>(fw_Wih, wfih16);
    conv_perm512<<<64, 256, 0, stream>>>(bw_Wih, wbih16);
    conv_perm512<<<64, 256, 0, stream>>>(fw_Whh, whh16);
    conv_perm512<<<64, 256, 0, stream>>>(bw_Whh, whh16 + 512 * 128);
    conv_f32_bf16<<<64, 256, 0, stream>>>(Wq, wq16, 65536 / 4);
    conv_f32_bf16<<<64, 256, 0, stream>>>(Wk, wk16, 65536 / 4);
    conv_f32_bf16<<<64, 256, 0, stream>>>(Wv, wv16, 65536 / 4);

    // xg = x @ Wih_p^T + biases -> [s][b][512] layout (M=32768, N=512, K=128)
    gemm_bt<1><<<dim3(256, 4), 256, 0, stream>>>(x16, wfih16, fw_bih, fw_bhh, xg, 128, 512);
    gemm_bt<1><<<dim3(256, 4), 256, 0, stream>>>(x16, wbih16, bw_bih, bw_bhh,
                                                 xg + (size_t)SS * BB * 512, 128, 512);
    // MFMA bidirectional scan -> h [b][s][256]
    lstm_scan_mfma<<<4, 1024, 0, stream>>>(whh16, xg, h);
    // q,k,v projections (M=32768, N=256, K=256)
    gemm_bt<0><<<dim3(256, 2), 256, 0, stream>>>(h, wq16, nullptr, nullptr, qb, 256, 256);
    gemm_bt<0><<<dim3(256, 2), 256, 0, stream>>>(h, wk16, nullptr, nullptr, kb, 256, 256);
    gemm_bt<0><<<dim3(256, 2), 256, 0, stream>>>(h, wv16, nullptr, nullptr, vb, 256, 256);
    transpose_v<<<dim3(16, 4, 32), 256, 0, stream>>>(vb, vT);
    // fused attention -> out fp32
    attn_kernel<<<dim3(16, 32), 256, 0, stream>>>(qb, kb, vT, (float*)d_out);
}

// Round 5
// 914.023 us; speedup vs baseline: 1.7605x; 1.7605x over previous
//
#include <hip/hip_runtime.h>

typedef unsigned short u16;
typedef unsigned int u32;
typedef __bf16 bf16x8 __attribute__((ext_vector_type(8)));
typedef bf16x8 __attribute__((may_alias)) bf16x8a;   // TBAA-safe vector loads
typedef float f32x4 __attribute__((ext_vector_type(4)));
typedef _Float16 f16;
typedef _Float16 f16x2 __attribute__((ext_vector_type(2)));

#define BB 32
#define SS 1024
#define HH 128
#define DD 256

__device__ __forceinline__ float b2f(u16 u) {
    u32 v = ((u32)u) << 16;
    return __builtin_bit_cast(float, v);
}
__device__ __forceinline__ u16 f2b(float f) {
    u32 u = __builtin_bit_cast(u32, f);
    u32 r = (u + 0x7fffu + ((u >> 16) & 1u)) >> 16;   // RNE
    return (u16)r;
}
__device__ __forceinline__ float sig_fast(float x) {
    return __builtin_amdgcn_rcpf(1.0f + __builtin_amdgcn_exp2f(-1.4426950408889634f * x));
}
__device__ __forceinline__ float tanh_fast(float x) {
    return 2.0f * sig_fast(2.0f * x) - 1.0f;
}

// ---------------------------------------------------------------------------
// fp32 -> bf16 conversion (grid-stride, float4 / ushort4)
// ---------------------------------------------------------------------------
__global__ __launch_bounds__(256) void conv_f32_bf16(
    const float* __restrict__ src, u16* __restrict__ dst, int n4)
{
    for (int i = blockIdx.x * 256 + threadIdx.x; i < n4; i += gridDim.x * 256) {
        float4 v = ((const float4*)src)[i];
        ushort4 o;
        o.x = f2b(v.x); o.y = f2b(v.y); o.z = f2b(v.z); o.w = f2b(v.w);
        ((ushort4*)dst)[i] = o;
    }
}

// ---------------------------------------------------------------------------
// fp32 -> bf16 with gate-interleave row permutation for [512][128] matrices:
// input row r = gate*128 + u -> output row u*4 + gate (bf16, for Wih GEMM).
// ---------------------------------------------------------------------------
__global__ __launch_bounds__(256) void conv_perm512(
    const float* __restrict__ src, u16* __restrict__ dst)
{
    for (int i = blockIdx.x * 256 + threadIdx.x; i < 512 * 128 / 4; i += gridDim.x * 256) {
        int r = i >> 5;
        int c4 = i & 31;
        int rp = ((r & 127) << 2) | (r >> 7);
        float4 v = ((const float4*)src)[i];
        ushort4 o;
        o.x = f2b(v.x); o.y = f2b(v.y); o.z = f2b(v.z); o.w = f2b(v.w);
        *(ushort4*)&dst[rp * 128 + c4 * 4] = o;
    }
}

// ---------------------------------------------------------------------------
// Same permutation but fp32 -> f16 (for the scan's resident Whh).
// ---------------------------------------------------------------------------
__global__ __launch_bounds__(256) void conv_perm512_f16(
    const float* __restrict__ src, u16* __restrict__ dst)
{
    for (int i = blockIdx.x * 256 + threadIdx.x; i < 512 * 128 / 4; i += gridDim.x * 256) {
        int r = i >> 5;
        int c4 = i & 31;
        int rp = ((r & 127) << 2) | (r >> 7);
        float4 v = ((const float4*)src)[i];
        ushort4 o;
        o.x = __builtin_bit_cast(u16, (f16)v.x);
        o.y = __builtin_bit_cast(u16, (f16)v.y);
        o.z = __builtin_bit_cast(u16, (f16)v.z);
        o.w = __builtin_bit_cast(u16, (f16)v.w);
        *(ushort4*)&dst[rp * 128 + c4 * 4] = o;
    }
}

// ---------------------------------------------------------------------------
// GEMM: C[M,N] = A[M,K] * Bt[N,K]^T, bf16 in, fp32 acc, bf16 out.
// 128x128 tile, BK=64, 256 thr = 4 waves (2x2), wave = 64x64.
// MODE 0: plain row-major store. MODE 1: xg store [s][b][col] + bias
// (bias index un-permuted since cols are gate-interleaved).
// ---------------------------------------------------------------------------
template <int MODE>
__global__ __launch_bounds__(256) void gemm_bt(
    const u16* __restrict__ A, const u16* __restrict__ Bt,
    const float* __restrict__ bias1, const float* __restrict__ bias2,
    u16* __restrict__ Cout, int K, int N)
{
    __shared__ u16 As[128 * 72];
    __shared__ u16 Bs[128 * 72];
    const int tid = threadIdx.x;
    const int lane = tid & 63, wave = tid >> 6;
    const int wm = wave >> 1, wn = wave & 1;
    const int lo = lane & 15, hi = lane >> 4;
    const int m0 = blockIdx.x * 128, n0 = blockIdx.y * 128;

    f32x4 acc[4][4] = {};

    for (int k0 = 0; k0 < K; k0 += 64) {
        __syncthreads();
#pragma unroll
        for (int i = 0; i < 4; i++) {
            int c = tid + 256 * i;
            int row = c >> 3, kc = (c & 7) * 8;
            *(uint4*)&As[row * 72 + kc] =
                *(const uint4*)&A[(size_t)(m0 + row) * K + k0 + kc];
            *(uint4*)&Bs[row * 72 + kc] =
                *(const uint4*)&Bt[(size_t)(n0 + row) * K + k0 + kc];
        }
        __syncthreads();
#pragma unroll
        for (int ks = 0; ks < 2; ks++) {
            bf16x8 af[4], bfr[4];
#pragma unroll
            for (int i = 0; i < 4; i++)
                af[i] = *(const bf16x8a*)&As[(wm * 64 + i * 16 + lo) * 72 + ks * 32 + hi * 8];
#pragma unroll
            for (int j = 0; j < 4; j++)
                bfr[j] = *(const bf16x8a*)&Bs[(wn * 64 + j * 16 + lo) * 72 + ks * 32 + hi * 8];
#pragma unroll
            for (int i = 0; i < 4; i++)
#pragma unroll
                for (int j = 0; j < 4; j++)
                    acc[i][j] = __builtin_amdgcn_mfma_f32_16x16x32_bf16(
                        af[i], bfr[j], acc[i][j], 0, 0, 0);
        }
    }
#pragma unroll
    for (int j = 0; j < 4; j++) {
        int col = n0 + wn * 64 + j * 16 + lo;
        float bsum = 0.f;
        if (MODE == 1) {
            int co = ((col & 3) << 7) | (col >> 2);   // un-permute for bias lookup
            bsum = bias1[co] + bias2[co];
        }
#pragma unroll
        for (int i = 0; i < 4; i++) {
            int row0 = m0 + wm * 64 + i * 16 + hi * 4;
#pragma unroll
            for (int r = 0; r < 4; r++) {
                float v = acc[i][j][r] + bsum;
                if (MODE == 1) {
                    int row = row0 + r;                 // = b*1024 + s
                    int sidx = row & 1023, bidx = row >> 10;
                    Cout[(size_t)sidx * (BB * 512) + bidx * 512 + col] = f2b(v);
                } else {
                    Cout[(size_t)(row0 + r) * N + col] = f2b(v);
                }
            }
        }
    }
}

// ---------------------------------------------------------------------------
// dot2 LSTM scan: 64 WGs (one per (dir,b) sequence), 256 threads = 4 waves.
// Thread t owns PERMUTED gate rows 2t, 2t+1 (unit u=t>>1; even lane: i,f;
// odd lane: g~,o). Whh rows resident in VGPRs as f16 pairs (128 VGPRs).
// h kept in LDS as f16[128] (256 B), read as 16 broadcast ds_read_b128 per
// thread, consumed by v_dot2_f32_f16 (fp32 accum). Gate-sum exchange via
// 2x shfl_xor(1); cell update in registers (redundant per lane pair).
// Double-buffered h -> one barrier per step.
// ---------------------------------------------------------------------------
__global__ __launch_bounds__(256, 1) void lstm_scan_dot2(
    const u16* __restrict__ Whh_h,   // [2][512][128] f16, rows permuted
    const u16* __restrict__ xg,      // [2][S][B][512] bf16, cols permuted
    u16* __restrict__ hout)          // [B][S][256] bf16; fw->[0:128], bw->[128:256]
{
    const int wg = blockIdx.x;
    const int b = wg & 31, dir = wg >> 5;
    const int t_ = threadIdx.x;          // 0..255
    const int u = t_ >> 1;               // hidden unit 0..127
    const bool odd = (t_ & 1) != 0;

    // resident weights: rows 2t, 2t+1 as 64 f16-pairs each
    u32 w0[64], w1[64];
    {
        const uint4* p0 = (const uint4*)(Whh_h + (size_t)dir * 512 * 128 + (size_t)(2 * t_) * 128);
        const uint4* p1 = (const uint4*)(Whh_h + (size_t)dir * 512 * 128 + (size_t)(2 * t_ + 1) * 128);
#pragma unroll
        for (int i = 0; i < 16; i++) {
            uint4 a = p0[i];
            w0[i * 4 + 0] = a.x; w0[i * 4 + 1] = a.y; w0[i * 4 + 2] = a.z; w0[i * 4 + 3] = a.w;
            uint4 c = p1[i];
            w1[i * 4 + 0] = c.x; w1[i * 4 + 1] = c.y; w1[i * 4 + 2] = c.z; w1[i * 4 + 3] = c.w;
        }
    }

    __shared__ __align__(16) u16 hbuf[2][128];   // f16 bits, double-buffered
    if (t_ < 128) hbuf[0][t_] = 0;
    float c = 0.0f;

    const u16* xgd = xg + (size_t)dir * SS * (BB * 512) + b * 512 + 2 * t_;
    u16* hop = hout + (size_t)b * SS * DD + dir * HH + u;

    int s = dir ? (SS - 1) : 0;
    const int dstep = dir ? -1 : 1;
    u32 xg_next = *(const u32*)&xgd[(size_t)s * (BB * 512)];
    __syncthreads();

    for (int t = 0; t < SS; t++) {
        u32 xv = xg_next;
        int s_next = s + dstep;
        if (t < SS - 1)
            xg_next = *(const u32*)&xgd[(size_t)s_next * (BB * 512)];  // prefetch

        float s0 = b2f((u16)(xv & 0xffff));      // row 2t sum (starts at xg)
        float s1 = b2f((u16)(xv >> 16));         // row 2t+1 sum

        const uint4* hb = (const uint4*)hbuf[t & 1];
#pragma unroll
        for (int i = 0; i < 16; i++) {
            uint4 hh = hb[i];                     // broadcast: all lanes same addr
            u32 hw[4] = {hh.x, hh.y, hh.z, hh.w};
#pragma unroll
            for (int j = 0; j < 4; j++) {
                f16x2 hv = __builtin_bit_cast(f16x2, hw[j]);
                s0 = __builtin_amdgcn_fdot2(hv, __builtin_bit_cast(f16x2, w0[i * 4 + j]), s0, false);
                s1 = __builtin_amdgcn_fdot2(hv, __builtin_bit_cast(f16x2, w1[i * 4 + j]), s1, false);
            }
        }

        // exchange with lane partner: even has (i,f), odd has (g~,o)
        float ax = __shfl_xor(s0, 1, 64);
        float bx = __shfl_xor(s1, 1, 64);
        float gi = odd ? ax : s0;
        float gf = odd ? bx : s1;
        float gg = odd ? s0 : ax;
        float go = odd ? s1 : bx;

        c = fmaf(sig_fast(gf), c, sig_fast(gi) * tanh_fast(gg));
        float h = sig_fast(go) * tanh_fast(c);

        if (!odd) {
            hbuf[(t + 1) & 1][u] = __builtin_bit_cast(u16, (f16)h);
            hop[(size_t)s * DD] = f2b(h);
        }
        __syncthreads();
        s = s_next;
    }
}

// ---------------------------------------------------------------------------
// V transpose: v[b][s][d] -> vT[b][d][s] via LDS tiles (64x64)
// ---------------------------------------------------------------------------
__global__ __launch_bounds__(256) void transpose_v(
    const u16* __restrict__ v, u16* __restrict__ vT)
{
    __shared__ u16 tile[64 * 72];
    const int b = blockIdx.z, s0 = blockIdx.x * 64, d0 = blockIdx.y * 64;
    const int tid = threadIdx.x;
#pragma unroll
    for (int i = 0; i < 2; i++) {
        int c = tid + 256 * i;
        int sl = c >> 3, dc = (c & 7) * 8;
        *(uint4*)&tile[sl * 72 + dc] =
            *(const uint4*)&v[((size_t)b * SS + s0 + sl) * DD + d0 + dc];
    }
    __syncthreads();
#pragma unroll
    for (int i = 0; i < 2; i++) {
        int c = tid + 256 * i;
        int dl = c >> 3, sc = (c & 7) * 8;
        u32 x0 = (u32)tile[(sc + 0) * 72 + dl] | ((u32)tile[(sc + 1) * 72 + dl] << 16);
        u32 x1 = (u32)tile[(sc + 2) * 72 + dl] | ((u32)tile[(sc + 3) * 72 + dl] << 16);
        u32 x2 = (u32)tile[(sc + 4) * 72 + dl] | ((u32)tile[(sc + 5) * 72 + dl] << 16);
        u32 x3 = (u32)tile[(sc + 6) * 72 + dl] | ((u32)tile[(sc + 7) * 72 + dl] << 16);
        uint4 val; val.x = x0; val.y = x1; val.z = x2; val.w = x3;
        *(uint4*)&vT[((size_t)b * DD + d0 + dl) * SS + s0 + sc] = val;
    }
}

// ---------------------------------------------------------------------------
// Flash attention: WG = (batch, 64-row q tile), 256 thr = 4 waves, each wave
// a 16-row stripe. KV tiles of 32. exp2-domain softmax, scale folded. f32 out.
// ---------------------------------------------------------------------------
__global__ __launch_bounds__(256) void attn_kernel(
    const u16* __restrict__ q, const u16* __restrict__ k,
    const u16* __restrict__ vT, float* __restrict__ out)
{
    __shared__ u16 Ks[32 * 264];
    __shared__ u16 Vs[256 * 40];
    __shared__ u16 Ps[64 * 40];
    const int b = blockIdx.y, q0 = blockIdx.x * 64;
    const int tid = threadIdx.x, wave = tid >> 6, lane = tid & 63;
    const int lo = lane & 15, hi = lane >> 4;
    const float c1 = 0.09016844005556021f;  // log2(e)/16

    bf16x8 qf[8];
    {
        const u16* qp = q + ((size_t)b * SS + q0 + wave * 16 + lo) * DD;
#pragma unroll
        for (int ks = 0; ks < 8; ks++)
            qf[ks] = *(const bf16x8a*)&qp[ks * 32 + hi * 8];
    }
    float m_i[4] = {-1e30f, -1e30f, -1e30f, -1e30f};
    float l_i[4] = {0.f, 0.f, 0.f, 0.f};
    f32x4 o[16] = {};

    for (int t0 = 0; t0 < SS; t0 += 32) {
        __syncthreads();
#pragma unroll
        for (int i = 0; i < 4; i++) {
            int c = tid + 256 * i;
            {
                int row = c >> 5, dc = (c & 31) * 8;
                *(uint4*)&Ks[row * 264 + dc] =
                    *(const uint4*)&k[((size_t)b * SS + t0 + row) * DD + dc];
            }
            {
                int d = c >> 2, sc = (c & 3) * 8;
                *(uint4*)&Vs[d * 40 + sc] =
                    *(const uint4*)&vT[((size_t)b * DD + d) * SS + t0 + sc];
            }
        }
        __syncthreads();

        f32x4 sacc[2] = {};
#pragma unroll
        for (int ks = 0; ks < 8; ks++) {
#pragma unroll
            for (int j = 0; j < 2; j++) {
                bf16x8 bfr = *(const bf16x8a*)&Ks[(j * 16 + lo) * 264 + ks * 32 + hi * 8];
                sacc[j] = __builtin_amdgcn_mfma_f32_16x16x32_bf16(qf[ks], bfr, sacc[j], 0, 0, 0);
            }
        }

        float tt[2][4];
#pragma unroll
        for (int j = 0; j < 2; j++)
#pragma unroll
            for (int r = 0; r < 4; r++) tt[j][r] = sacc[j][r] * c1;
        float rm[4];
#pragma unroll
        for (int r = 0; r < 4; r++) rm[r] = fmaxf(tt[0][r], tt[1][r]);
#pragma unroll
        for (int mm = 1; mm <= 8; mm <<= 1)
#pragma unroll
            for (int r = 0; r < 4; r++) rm[r] = fmaxf(rm[r], __shfl_xor(rm[r], mm, 64));
        float al[4], rs[4];
#pragma unroll
        for (int r = 0; r < 4; r++) {
            float mn = fmaxf(m_i[r], rm[r]);
            al[r] = __builtin_amdgcn_exp2f(m_i[r] - mn);
            m_i[r] = mn;
            rs[r] = 0.f;
        }
#pragma unroll
        for (int j = 0; j < 2; j++)
#pragma unroll
            for (int r = 0; r < 4; r++) {
                float p = __builtin_amdgcn_exp2f(tt[j][r] - m_i[r]);
                rs[r] += p;
                Ps[(wave * 16 + hi * 4 + r) * 40 + j * 16 + lo] = f2b(p);
            }
#pragma unroll
        for (int mm = 1; mm <= 8; mm <<= 1)
#pragma unroll
            for (int r = 0; r < 4; r++) rs[r] += __shfl_xor(rs[r], mm, 64);
#pragma unroll
        for (int r = 0; r < 4; r++) l_i[r] = l_i[r] * al[r] + rs[r];
#pragma unroll
        for (int nt = 0; nt < 16; nt++) {
            o[nt][0] *= al[0]; o[nt][1] *= al[1];
            o[nt][2] *= al[2]; o[nt][3] *= al[3];
        }
        __syncthreads();   // order u16 Ps stores vs vector reload
        bf16x8 pa = *(const bf16x8a*)&Ps[(wave * 16 + lo) * 40 + hi * 8];
#pragma unroll
        for (int nt = 0; nt < 16; nt++) {
            bf16x8 bv = *(const bf16x8a*)&Vs[(nt * 16 + lo) * 40 + hi * 8];
            o[nt] = __builtin_amdgcn_mfma_f32_16x16x32_bf16(pa, bv, o[nt], 0, 0, 0);
        }
    }
    float inv[4];
#pragma unroll
    for (int r = 0; r < 4; r++) inv[r] = __builtin_amdgcn_rcpf(l_i[r]);
#pragma unroll
    for (int nt = 0; nt < 16; nt++)
#pragma unroll
        for (int r = 0; r < 4; r++) {
            int row = q0 + wave * 16 + hi * 4 + r;
            int col = nt * 16 + lo;
            out[((size_t)b * SS + row) * DD + col] = o[nt][r] * inv[r];
        }
}

// ---------------------------------------------------------------------------
extern "C" void kernel_launch(void* const* d_in, const int* in_sizes, int n_in,
                              void* d_out, int out_size, void* d_ws, size_t ws_size,
                              hipStream_t stream)
{
    (void)in_sizes; (void)n_in; (void)out_size;
    const float* x      = (const float*)d_in[0];
    const float* fw_Wih = (const float*)d_in[1];
    const float* fw_Whh = (const float*)d_in[2];
    const float* fw_bih = (const float*)d_in[3];
    const float* fw_bhh = (const float*)d_in[4];
    const float* bw_Wih = (const float*)d_in[5];
    const float* bw_Whh = (const float*)d_in[6];
    const float* bw_bih = (const float*)d_in[7];
    const float* bw_bhh = (const float*)d_in[8];
    const float* Wq = (const float*)d_in[9];
    const float* Wk = (const float*)d_in[10];
    const float* Wv = (const float*)d_in[11];

    // Workspace layout (total 143,523,840 B; ws proven >= 201 MB in r1/r2):
    //   [0, 67108864)    xg bf16 [2][S][B][512], cols gate-interleaved
    //                    (dead after scan; vb aliases)
    //   +67108864        h   bf16 [32768][256]
    //   +83886080        qb
    //   +100663296       kb
    //   +117440512       vT
    //   +134217728       x16 bf16 [32768][128]
    //   +142606336       weights: fwWih_p, bwWih_p, wq, wk, wv (bf16),
    //                    Whh f16 permuted [2][512][128] (131072 B each slot)
    if (ws_size < 143523840ULL) return;

    char* ws = (char*)d_ws;
    u16* xg  = (u16*)ws;
    u16* h   = (u16*)(ws + 67108864);
    u16* qb  = (u16*)(ws + 83886080);
    u16* kb  = (u16*)(ws + 100663296);
    u16* vT  = (u16*)(ws + 117440512);
    u16* x16 = (u16*)(ws + 134217728);
    u16* wfih16 = (u16*)(ws + 142606336);
    u16* wbih16 = (u16*)(ws + 142606336 + 131072);
    u16* wq16   = (u16*)(ws + 142606336 + 262144);
    u16* wk16   = (u16*)(ws + 142606336 + 393216);
    u16* wv16   = (u16*)(ws + 142606336 + 524288);
    u16* whhf16 = (u16*)(ws + 142606336 + 655360);   // [2][512][128] f16
    u16* vb = (u16*)ws;                              // aliases xg (dead after scan)

    conv_f32_bf16<<<1024, 256, 0, stream>>>(x, x16, (BB * SS * HH) / 4);
    conv_perm512<<<64, 256, 0, stream>>>(fw_Wih, wfih16);
    conv_perm512<<<64, 256, 0, stream>>>(bw_Wih, wbih16);
    conv_perm512_f16<<<64, 256, 0, stream>>>(fw_Whh, whhf16);
    conv_perm512_f16<<<64, 256, 0, stream>>>(bw_Whh, whhf16 + 512 * 128);
    conv_f32_bf16<<<64, 256, 0, stream>>>(Wq, wq16, 65536 / 4);
    conv_f32_bf16<<<64, 256, 0, stream>>>(Wk, wk16, 65536 / 4);
    conv_f32_bf16<<<64, 256, 0, stream>>>(Wv, wv16, 65536 / 4);

    // xg = x @ Wih_p^T + biases -> [s][b][512] permuted-col layout
    gemm_bt<1><<<dim3(256, 4), 256, 0, stream>>>(x16, wfih16, fw_bih, fw_bhh, xg, 128, 512);
    gemm_bt<1><<<dim3(256, 4), 256, 0, stream>>>(x16, wbih16, bw_bih, bw_bhh,
                                                 xg + (size_t)SS * BB * 512, 128, 512);
    // dot2 bidirectional scan -> h [b][s][256]
    lstm_scan_dot2<<<64, 256, 0, stream>>>(whhf16, xg, h);
    // q,k,v projections (M=32768, N=256, K=256)
    gemm_bt<0><<<dim3(256, 2), 256, 0, stream>>>(h, wq16, nullptr, nullptr, qb, 256, 256);
    gemm_bt<0><<<dim3(256, 2), 256, 0, stream>>>(h, wk16, nullptr, nullptr, kb, 256, 256);
    gemm_bt<0><<<dim3(256, 2), 256, 0, stream>>>(h, wv16, nullptr, nullptr, vb, 256, 256);
    transpose_v<<<dim3(16, 4, 32), 256, 0, stream>>>(vb, vT);
    // fused attention -> out fp32
    attn_kernel<<<dim3(16, 32), 256, 0, stream>>>(qb, kb, vT, (float*)d_out);
}